// Round 10
// baseline (993.705 us; speedup 1.0000x reference)
//
#include <hip/hip_runtime.h>

#define NPT  4096
#define NBLK 256
#define NTHR 1024

constexpr float EPSV   = 1e-4f;
constexpr float LN2F   = 0.69314718055994531f;
constexpr float E2     = EPSV * LN2F;          // eps*ln2
constexpr float INV_E2 = 1.0f / E2;            // 1/(eps*ln2)
constexpr float S_U    = 4.0f / LN2F;          // uniformity scale

// LDS layout (floats):
//   packx : float4[4096] [0,16384)      (x,y,z,G) per x-point
//   packy : float4[4096] [16384,32768)  (x,y,z,G) per y-point
//   part2 : float2[1024] [32768,34816)  per-row (m,s) partials [lrow][half*8+oct]
// xyz persistent; only .w (scaled potential G) restaged per step (ds_write_b32).
#define SMEM_FLOATS 34816
#define SMEM_BYTES  (SMEM_FLOATS * 4)

// ws float offsets
#define WF    0
#define WG    4096
#define WPX0  8192
#define WPX1  12288
#define WPY0  16384
#define WPY1  20480
#define WFFIN 24576
#define WFXV  28672
#define WFYV  32768
#define WULS  36864
#define WCTR  40960     // 512 uints
#define WCNX  41984     // float[4096]: 0.5*||x_i||^2
#define WCNY  46080     // float[4096]: 0.5*||y_j||^2  (end 50176 floats = 200 KB)

__device__ __forceinline__ float fexp2(float x) { return __builtin_amdgcn_exp2f(x); }
__device__ __forceinline__ float flog2(float x) { return __builtin_amdgcn_logf(x); }

__device__ __forceinline__ float max3f(float a, float b, float c) {
    float d;
    asm("v_max3_f32 %0, %1, %2, %3" : "=v"(d) : "v"(a), "v"(b), "v"(c));
    return d;
}

// VALU-only cross-lane via DPP (no LDS pipe): xor1, xor2, row_half_mirror.
template<int CTRL>
__device__ __forceinline__ float dppf(float x) {
    return __int_as_float(__builtin_amdgcn_update_dpp(
        __float_as_int(x), __float_as_int(x), CTRL, 0xF, 0xF, false));
}

// system-scope (sc0 sc1) relaxed accessors: bypass non-coherent XCD L2s.
__device__ __forceinline__ float gload(const float* p) {
    return __hip_atomic_load(p, __ATOMIC_RELAXED, __HIP_MEMORY_SCOPE_SYSTEM);
}
__device__ __forceinline__ void gstore(float* p, float v) {
    __hip_atomic_store(p, v, __ATOMIC_RELAXED, __HIP_MEMORY_SCOPE_SYSTEM);
}

// Fence-free GROUP barrier (128 blocks/group). 256x1024, 1 block/CU is the
// proven-safe residency envelope (R8's 2-block/CU deadlocked).
__device__ __forceinline__ void group_barrier(unsigned* base, unsigned target, int b) {
    asm volatile("s_waitcnt vmcnt(0)" ::: "memory");
    __syncthreads();
    if (threadIdx.x == 0) {
        __hip_atomic_fetch_add(&base[(b & 15) * 16], 1u,
                               __ATOMIC_RELAXED, __HIP_MEMORY_SCOPE_SYSTEM);
        for (;;) {
            unsigned tot = 0;
#pragma unroll
            for (int i = 0; i < 16; ++i)
                tot += __hip_atomic_load(&base[i * 16],
                                         __ATOMIC_RELAXED, __HIP_MEMORY_SCOPE_SYSTEM);
            if (tot >= target) break;
            __builtin_amdgcn_s_sleep(1);
        }
    }
    __syncthreads();
}

// One wave: log2-LSE for 4 ROWS over 2048 columns (one half).
// One ds_read_b128 per column amortized over 4 rows; chunk=4 cols keeps
// av[4][4]+xs+state ~54 VGPR (fits the immovable 64-VGPR cap, no spill).
template<bool ISU>
__device__ __forceinline__ void run_task(
    const float4* __restrict__ colpk, const float4* __restrict__ rowpk,
    int r0g, int half, int lane, float scale, float2* part2, int lr0)
{
    float xs0[4], xs1[4], xs2[4];
#pragma unroll
    for (int r = 0; r < 4; ++r) {
        float4 q = rowpk[r0g + r];
        xs0[r] = q.x * scale; xs1[r] = q.y * scale; xs2[r] = q.z * scale;
    }
    float m[4], s[4];
    const int cbase = half * 2048 + lane;
    const float4* col = colpk + cbase;

#pragma unroll
    for (int chunk = 0; chunk < 8; ++chunk) {
        float av[4][4];
        float mc[4] = {-1e30f, -1e30f, -1e30f, -1e30f};
#pragma unroll
        for (int k = 0; k < 4; ++k) {
            const float4 c = col[(chunk * 4 + k) * 64];
#pragma unroll
            for (int r = 0; r < 4; ++r) {
                float a = fmaf(xs0[r], c.x, c.w);
                a = fmaf(xs1[r], c.y, a);
                a = fmaf(xs2[r], c.z, a);
                if (ISU) {
                    const int j = cbase + (chunk * 4 + k) * 64;
                    if (j == r0g + r) a = -1e30f;   // mask diagonal
                }
                av[r][k] = a;
                mc[r] = fmaxf(mc[r], a);
            }
        }
#pragma unroll
        for (int r = 0; r < 4; ++r) {
            float sc_ = fexp2(av[r][0] - mc[r]) + fexp2(av[r][1] - mc[r])
                      + fexp2(av[r][2] - mc[r]) + fexp2(av[r][3] - mc[r]);
            if (chunk == 0) { m[r] = mc[r]; s[r] = sc_; }
            else {
                float dd = m[r] - mc[r];
                float e = fexp2(-fabsf(dd));
                float bigs   = (dd >= 0.0f) ? s[r] : sc_;
                float smalls = (dd >= 0.0f) ? sc_  : s[r];
                s[r] = fmaf(smalls, e, bigs);
                m[r] = fmaxf(m[r], mc[r]);
            }
        }
    }
    // ---- VALU-only DPP reduction to 8-lane partials ----
#pragma unroll
    for (int r = 0; r < 4; ++r) {
        const float ml = m[r];
        float mm = m[r];
        mm = fmaxf(mm, dppf<0xB1>(mm));
        mm = fmaxf(mm, dppf<0x4E>(mm));
        mm = fmaxf(mm, dppf<0x141>(mm));
        float ssv = s[r] * fexp2(ml - mm);
        ssv += dppf<0xB1>(ssv);
        ssv += dppf<0x4E>(ssv);
        ssv += dppf<0x141>(ssv);
        if ((lane & 7) == 0)
            part2[(lr0 + r) * 16 + half * 8 + (lane >> 3)] = make_float2(mm, ssv);
    }
}

__global__ void sink_init(const float* __restrict__ xin, const float* __restrict__ yin,
                          float* __restrict__ ws) {
    int t = blockIdx.x * blockDim.x + threadIdx.x;
    if (t < NPT) {
        gstore(ws + WF + t, 0.0f);
        gstore(ws + WG + t, 0.0f);
        gstore(ws + WPX0 + t, 0.0f);
        gstore(ws + WPY0 + t, 0.0f);
        float x0 = xin[3 * t], y0 = xin[3 * t + 1], z0 = xin[3 * t + 2];
        ws[WCNX + t] = 0.5f * (x0 * x0 + y0 * y0 + z0 * z0);
        float4 v = ((const float4*)yin)[t];
        ws[WCNY + t] = 0.5f * (v.x * v.x + v.y * v.y + v.z * v.z);
    }
    if (t < 512) {
        __hip_atomic_store((unsigned*)(ws + WCTR) + t, 0u,
                           __ATOMIC_RELAXED, __HIP_MEMORY_SCOPE_SYSTEM);
    }
}

__global__ __launch_bounds__(NTHR)
__attribute__((amdgpu_waves_per_eu(4, 4)))
void sink_main(
    const float* __restrict__ xin, const float* __restrict__ yin,
    float* __restrict__ ws, float* __restrict__ out)
{
    extern __shared__ float smem[];
    float4* packx = (float4*)smem;
    float4* packy = (float4*)(smem + 16384);
    float2* part2 = (float2*)(smem + 32768);

    float* f    = ws + WF;
    float* g    = ws + WG;
    float* px0  = ws + WPX0;
    float* px1  = ws + WPX1;
    float* py0  = ws + WPY0;
    float* py1  = ws + WPY1;
    float* ffin = ws + WFFIN;
    float* fxv  = ws + WFXV;
    float* fyv  = ws + WFYV;
    float* uls  = ws + WULS;
    unsigned* ctrA = (unsigned*)(ws + WCTR);
    unsigned* ctrB = (unsigned*)(ws + WCTR) + 256;
    const float* cnx = ws + WCNX;
    const float* cny = ws + WCNY;

    const int tid  = threadIdx.x;
    const int b    = blockIdx.x;
    const int wave = tid >> 6;
    const int lane = tid & 63;
    unsigned* cbarrier = (b < 128) ? ctrA : ctrB;

    // Stage xyz into LDS packs once (w filled per step).
    for (int i = tid; i < NPT; i += NTHR) {
        packx[i] = make_float4(xin[3 * i], xin[3 * i + 1], xin[3 * i + 2], 0.0f);
        float4 v = ((const float4*)yin)[i];
        packy[i] = make_float4(v.x, v.y, v.z, 0.0f);
    }
    __syncthreads();

    for (int h = 0; h <= 40; ++h) {
        // ---- decode this block's chain for this step ----
        bool rows_x, cols_x, isU = false, avg = false;
        const float* pot; float* outp; float scale = INV_E2;
        int row0g, rows_pb;
        if (h == 0) {
            if (b < 128)      { rows_x = true;  cols_x = false; pot = g;    outp = f;    rows_pb = 32; row0g = b * 32; }
            else if (b < 192) { rows_x = true;  cols_x = true;  pot = px0;  outp = px1;  avg = true; rows_pb = 64; row0g = (b - 128) * 64; }
            else              { rows_x = true;  cols_x = true;  pot = nullptr; outp = uls; isU = true; scale = S_U; rows_pb = 64; row0g = (b - 192) * 64; }
        } else if (h == 40) {
            if (b < 128)      { rows_x = true;  cols_x = false; pot = g;    outp = ffin; rows_pb = 32; row0g = b * 32; }
            else if (b < 192) { rows_x = true;  cols_x = true;  pot = px0;  outp = fxv;  rows_pb = 64; row0g = (b - 128) * 64; }
            else              { rows_x = false; cols_x = false; pot = py0;  outp = fyv;  rows_pb = 64; row0g = (b - 192) * 64; }
        } else if (h & 1) {
            int k = (h - 1) >> 1;   // yy iteration
            if (b < 128) { rows_x = false; cols_x = true;  pot = f; outp = g; rows_pb = 32; row0g = b * 32; }
            else         { rows_x = false; cols_x = false; pot = (k & 1) ? py1 : py0; outp = (k & 1) ? py0 : py1; avg = true; rows_pb = 32; row0g = (b - 128) * 32; }
        } else {
            int k = h >> 1;         // xx iteration
            if (b < 128) { rows_x = true; cols_x = false; pot = g; outp = f; rows_pb = 32; row0g = b * 32; }
            else         { rows_x = true; cols_x = true;  pot = (k & 1) ? px1 : px0; outp = (k & 1) ? px0 : px1; avg = true; rows_pb = 32; row0g = (b - 128) * 32; }
        }

        // ---- restage G (.w) of the active column pack: pot - cn, scaled ----
        float4* colpk = cols_x ? packx : packy;
        const float* ccn = cols_x ? cnx : cny;
        for (int j = tid; j < NPT; j += NTHR) {
            float pv = pot ? gload(pot + j) : 0.0f;
            float cn = ccn[j];
            ((float*)&colpk[j])[3] = (pv - cn) * scale;   // ds_write_b32
        }
        __syncthreads();

        // ---- wave tasks: 4 rows x 2048 cols each ----
        const float4* rowpk = rows_x ? packx : packy;
        const int ntask = rows_pb >> 1;          // (rows_pb/4 groups) x 2 halves
        for (int t = wave; t < ntask; t += 16) {
            int grp = t >> 1, half = t & 1;
            int lr0 = grp << 2;
            int r0g = row0g + lr0;
            if (isU) run_task<true >(colpk, rowpk, r0g, half, lane, scale, part2, lr0);
            else     run_task<false>(colpk, rowpk, r0g, half, lane, scale, part2, lr0);
        }
        __syncthreads();

        // ---- finalize: merge 16 partials (max tree + pipelined exp2 sum) ----
        const float* rcn = rows_x ? cnx : cny;
        if (tid < rows_pb) {
            float2 pv2[16];
#pragma unroll
            for (int q = 0; q < 16; ++q) pv2[q] = part2[tid * 16 + q];
            float mm = pv2[0].x;
#pragma unroll
            for (int q = 1; q < 15; q += 2) mm = max3f(mm, pv2[q].x, pv2[q + 1].x);
            mm = fmaxf(mm, pv2[15].x);
            float ss = 0.0f;
#pragma unroll
            for (int q = 0; q < 16; ++q) ss += pv2[q].y * fexp2(pv2[q].x - mm);
            int rg = row0g + tid;
            float rn = rcn[rg];
            float lse2 = mm + flog2(ss) - rn * scale;    // + X_i
            float val;
            if (isU) {
                val = lse2;
            } else {
                val = -E2 * (lse2 - 12.0f);               // log2(4096)=12
                if (avg) val = 0.5f * (gload(pot + rg) + val);
            }
            gstore(outp + rg, val);
        }

        group_barrier(cbarrier, 128u * (unsigned)(h + 1), b);
    }

    // ---- final reduction (block 0; must also wait for group B) ----
    if (b == 0) {
        if (tid == 0) {
            for (;;) {
                unsigned tot = 0;
#pragma unroll
                for (int i = 0; i < 16; ++i)
                    tot += __hip_atomic_load(&ctrB[i * 16],
                                             __ATOMIC_RELAXED, __HIP_MEMORY_SCOPE_SYSTEM);
                if (tot >= 128u * 41u) break;
                __builtin_amdgcn_s_sleep(1);
            }
        }
        __syncthreads();

        float sf = 0.f, sg = 0.f, sx = 0.f, sy = 0.f, um = -1e30f, us = 0.f;
        for (int i = tid; i < NPT; i += NTHR) {
            sf += gload(ffin + i); sg += gload(g + i);
            sx += gload(fxv + i);  sy += gload(fyv + i);
            float v = gload(uls + i);
            float mn = fmaxf(um, v);
            us = us * fexp2(um - mn) + fexp2(v - mn);
            um = mn;
        }
#pragma unroll
        for (int off = 1; off < 64; off <<= 1) {
            sf += __shfl_xor(sf, off, 64);
            sg += __shfl_xor(sg, off, 64);
            sx += __shfl_xor(sx, off, 64);
            sy += __shfl_xor(sy, off, 64);
            float mo = __shfl_xor(um, off, 64);
            float so = __shfl_xor(us, off, 64);
            float mn = fmaxf(um, mo);
            us = us * fexp2(um - mn) + so * fexp2(mo - mn);
            um = mn;
        }
        __syncthreads();
        if (lane == 0) {
            float* red = smem;
            red[wave * 6 + 0] = sf; red[wave * 6 + 1] = sg; red[wave * 6 + 2] = sx;
            red[wave * 6 + 3] = sy; red[wave * 6 + 4] = um; red[wave * 6 + 5] = us;
        }
        __syncthreads();
        if (tid == 0) {
            float* red = smem;
            float Sf = 0, Sg = 0, Sx = 0, Sy = 0, Um = -1e30f, Us = 0;
            for (int w = 0; w < 16; ++w) {
                Sf += red[w * 6 + 0]; Sg += red[w * 6 + 1];
                Sx += red[w * 6 + 2]; Sy += red[w * 6 + 3];
                float mo = red[w * 6 + 4], so = red[w * 6 + 5];
                float mn = fmaxf(Um, mo);
                Us = Us * fexp2(Um - mn) + so * fexp2(mo - mn);
                Um = mn;
            }
            float mean = (Sf + Sg - Sx - Sy) * (1.0f / 4096.0f);
            float U = LN2F * (Um + flog2(Us)) - logf(4096.0f * 4095.0f);
            out[0] = mean + U;
        }
    }
}

extern "C" void kernel_launch(void* const* d_in, const int* in_sizes, int n_in,
                              void* d_out, int out_size, void* d_ws, size_t ws_size,
                              hipStream_t stream) {
    const float* x = (const float*)d_in[0];
    const float* y = (const float*)d_in[1];
    float* ws  = (float*)d_ws;
    float* out = (float*)d_out;

    (void)hipFuncSetAttribute((const void*)sink_main,
                              hipFuncAttributeMaxDynamicSharedMemorySize, SMEM_BYTES);

    sink_init<<<4, 1024, 0, stream>>>(x, y, ws);
    sink_main<<<NBLK, NTHR, SMEM_BYTES, stream>>>(x, y, ws, out);
}

// Round 11
// 571.897 us; speedup vs baseline: 1.7376x; 1.7376x over previous
//
#include <hip/hip_runtime.h>

#define NPT  4096
#define NBLK 256
#define NTHR 1024

constexpr float EPSV   = 1e-4f;
constexpr float LN2F   = 0.69314718055994531f;
constexpr float E2     = EPSV * LN2F;          // eps*ln2
constexpr float INV_E2 = 1.0f / E2;            // 1/(eps*ln2)
constexpr float S_U    = 4.0f / LN2F;          // uniformity scale

// LDS layout (floats):
//   packx : float4[4096] [0,16384)      (x,y,z,G) per x-point
//   packy : float4[4096] [16384,32768)  (x,y,z,G) per y-point
//   part2 : float2[1024] [32768,34816)  per-row (m,s) partials [lrow][half*8+oct]
// xyz persistent; only .w (scaled potential G) restaged per step (ds_write_b32).
#define SMEM_FLOATS 34816
#define SMEM_BYTES  (SMEM_FLOATS * 4)

// ws float offsets
#define WF    0
#define WG    4096
#define WPX0  8192
#define WPX1  12288
#define WPY0  16384
#define WPY1  20480
#define WFFIN 24576
#define WFXV  28672
#define WFYV  32768
#define WULS  36864
#define WCTR  40960     // 512 uints
#define WCNX  41984     // float[4096]: 0.5*||x_i||^2
#define WCNY  46080     // float[4096]: 0.5*||y_j||^2

__device__ __forceinline__ float fexp2(float x) { return __builtin_amdgcn_exp2f(x); }
__device__ __forceinline__ float flog2(float x) { return __builtin_amdgcn_logf(x); }

__device__ __forceinline__ float max3f(float a, float b, float c) {
    float d;
    asm("v_max3_f32 %0, %1, %2, %3" : "=v"(d) : "v"(a), "v"(b), "v"(c));
    return d;
}

// VALU-only cross-lane via DPP (no LDS pipe): xor1, xor2, row_half_mirror.
template<int CTRL>
__device__ __forceinline__ float dppf(float x) {
    return __int_as_float(__builtin_amdgcn_update_dpp(
        __float_as_int(x), __float_as_int(x), CTRL, 0xF, 0xF, false));
}

// system-scope (sc0 sc1) relaxed accessors: bypass non-coherent XCD L2s.
__device__ __forceinline__ float gload(const float* p) {
    return __hip_atomic_load(p, __ATOMIC_RELAXED, __HIP_MEMORY_SCOPE_SYSTEM);
}
__device__ __forceinline__ void gstore(float* p, float v) {
    __hip_atomic_store(p, v, __ATOMIC_RELAXED, __HIP_MEMORY_SCOPE_SYSTEM);
}

// Fence-free GROUP barrier (128 blocks/group). 256x1024, 1 block/CU is the
// proven-safe residency envelope (R8's 2-block/CU deadlocked).
__device__ __forceinline__ void group_barrier(unsigned* base, unsigned target, int b) {
    asm volatile("s_waitcnt vmcnt(0)" ::: "memory");
    __syncthreads();
    if (threadIdx.x == 0) {
        __hip_atomic_fetch_add(&base[(b & 15) * 16], 1u,
                               __ATOMIC_RELAXED, __HIP_MEMORY_SCOPE_SYSTEM);
        for (;;) {
            unsigned tot = 0;
#pragma unroll
            for (int i = 0; i < 16; ++i)
                tot += __hip_atomic_load(&base[i * 16],
                                         __ATOMIC_RELAXED, __HIP_MEMORY_SCOPE_SYSTEM);
            if (tot >= target) break;
            __builtin_amdgcn_s_sleep(1);
        }
    }
    __syncthreads();
}

// One wave: log2-LSE for 4 ROWS over 2048 columns (one half).
// One ds_read_b128 per column amortized over 4 rows. The chunk loop is
// NOT unrolled (#pragma unroll 1): R10 proved full unroll merges chunks'
// live ranges and spills past the immovable 64-VGPR cap.
template<bool ISU>
__device__ __forceinline__ void run_task(
    const float4* __restrict__ colpk, const float4* __restrict__ rowpk,
    int r0g, int half, int lane, float scale, float2* part2, int lr0)
{
    float xs0[4], xs1[4], xs2[4];
#pragma unroll
    for (int r = 0; r < 4; ++r) {
        float4 q = rowpk[r0g + r];
        xs0[r] = q.x * scale; xs1[r] = q.y * scale; xs2[r] = q.z * scale;
    }
    float m[4] = {-1e30f, -1e30f, -1e30f, -1e30f};
    float s[4] = {0.0f, 0.0f, 0.0f, 0.0f};
    const int cbase = half * 2048 + lane;
    const float4* col = colpk + cbase;
    int jbase = cbase;

#pragma unroll 1
    for (int chunk = 0; chunk < 8; ++chunk) {
        float av[4][4];
        float mc[4] = {-1e30f, -1e30f, -1e30f, -1e30f};
#pragma unroll
        for (int k = 0; k < 4; ++k) {
            const float4 c = col[k * 64];           // imm offsets 0..3072 B
#pragma unroll
            for (int r = 0; r < 4; ++r) {
                float a = fmaf(xs0[r], c.x, c.w);
                a = fmaf(xs1[r], c.y, a);
                a = fmaf(xs2[r], c.z, a);
                if (ISU) {
                    if (jbase + k * 64 == r0g + r) a = -1e30f;   // mask diagonal
                }
                av[r][k] = a;
                mc[r] = fmaxf(mc[r], a);
            }
        }
#pragma unroll
        for (int r = 0; r < 4; ++r) {
            float sc_ = fexp2(av[r][0] - mc[r]) + fexp2(av[r][1] - mc[r])
                      + fexp2(av[r][2] - mc[r]) + fexp2(av[r][3] - mc[r]);
            float dd = m[r] - mc[r];
            float e = fexp2(-fabsf(dd));
            float bigs   = (dd >= 0.0f) ? s[r] : sc_;
            float smalls = (dd >= 0.0f) ? sc_  : s[r];
            s[r] = fmaf(smalls, e, bigs);           // chunk0: s=0 -> s=sc_*e'... 
            m[r] = fmaxf(m[r], mc[r]);              // (m=-1e30 -> e=exp2(-inf)=0, bigs=sc_) ok
        }
        col += 256; jbase += 256;
    }
    // ---- VALU-only DPP reduction to 8-lane partials ----
#pragma unroll
    for (int r = 0; r < 4; ++r) {
        const float ml = m[r];
        float mm = m[r];
        mm = fmaxf(mm, dppf<0xB1>(mm));
        mm = fmaxf(mm, dppf<0x4E>(mm));
        mm = fmaxf(mm, dppf<0x141>(mm));
        float ssv = s[r] * fexp2(ml - mm);
        ssv += dppf<0xB1>(ssv);
        ssv += dppf<0x4E>(ssv);
        ssv += dppf<0x141>(ssv);
        if ((lane & 7) == 0)
            part2[(lr0 + r) * 16 + half * 8 + (lane >> 3)] = make_float2(mm, ssv);
    }
}

__global__ void sink_init(const float* __restrict__ xin, const float* __restrict__ yin,
                          float* __restrict__ ws) {
    int t = blockIdx.x * blockDim.x + threadIdx.x;
    if (t < NPT) {
        gstore(ws + WF + t, 0.0f);
        gstore(ws + WG + t, 0.0f);
        gstore(ws + WPX0 + t, 0.0f);
        gstore(ws + WPY0 + t, 0.0f);
        float x0 = xin[3 * t], y0 = xin[3 * t + 1], z0 = xin[3 * t + 2];
        ws[WCNX + t] = 0.5f * (x0 * x0 + y0 * y0 + z0 * z0);
        float4 v = ((const float4*)yin)[t];
        ws[WCNY + t] = 0.5f * (v.x * v.x + v.y * v.y + v.z * v.z);
    }
    if (t < 512) {
        __hip_atomic_store((unsigned*)(ws + WCTR) + t, 0u,
                           __ATOMIC_RELAXED, __HIP_MEMORY_SCOPE_SYSTEM);
    }
}

__global__ __launch_bounds__(NTHR)
__attribute__((amdgpu_waves_per_eu(4, 4)))
void sink_main(
    const float* __restrict__ xin, const float* __restrict__ yin,
    float* __restrict__ ws, float* __restrict__ out)
{
    extern __shared__ float smem[];
    float4* packx = (float4*)smem;
    float4* packy = (float4*)(smem + 16384);
    float2* part2 = (float2*)(smem + 32768);

    float* f    = ws + WF;
    float* g    = ws + WG;
    float* px0  = ws + WPX0;
    float* px1  = ws + WPX1;
    float* py0  = ws + WPY0;
    float* py1  = ws + WPY1;
    float* ffin = ws + WFFIN;
    float* fxv  = ws + WFXV;
    float* fyv  = ws + WFYV;
    float* uls  = ws + WULS;
    unsigned* ctrA = (unsigned*)(ws + WCTR);
    unsigned* ctrB = (unsigned*)(ws + WCTR) + 256;
    const float* cnx = ws + WCNX;
    const float* cny = ws + WCNY;

    const int tid  = threadIdx.x;
    const int b    = blockIdx.x;
    const int wave = tid >> 6;
    const int lane = tid & 63;
    unsigned* cbarrier = (b < 128) ? ctrA : ctrB;

    // Stage xyz into LDS packs once (w filled per step).
    for (int i = tid; i < NPT; i += NTHR) {
        packx[i] = make_float4(xin[3 * i], xin[3 * i + 1], xin[3 * i + 2], 0.0f);
        float4 v = ((const float4*)yin)[i];
        packy[i] = make_float4(v.x, v.y, v.z, 0.0f);
    }
    __syncthreads();

    for (int h = 0; h <= 40; ++h) {
        // ---- decode this block's chain for this step ----
        bool rows_x, cols_x, isU = false, avg = false;
        const float* pot; float* outp; float scale = INV_E2;
        int row0g, rows_pb;
        if (h == 0) {
            if (b < 128)      { rows_x = true;  cols_x = false; pot = g;    outp = f;    rows_pb = 32; row0g = b * 32; }
            else if (b < 192) { rows_x = true;  cols_x = true;  pot = px0;  outp = px1;  avg = true; rows_pb = 64; row0g = (b - 128) * 64; }
            else              { rows_x = true;  cols_x = true;  pot = nullptr; outp = uls; isU = true; scale = S_U; rows_pb = 64; row0g = (b - 192) * 64; }
        } else if (h == 40) {
            if (b < 128)      { rows_x = true;  cols_x = false; pot = g;    outp = ffin; rows_pb = 32; row0g = b * 32; }
            else if (b < 192) { rows_x = true;  cols_x = true;  pot = px0;  outp = fxv;  rows_pb = 64; row0g = (b - 128) * 64; }
            else              { rows_x = false; cols_x = false; pot = py0;  outp = fyv;  rows_pb = 64; row0g = (b - 192) * 64; }
        } else if (h & 1) {
            int k = (h - 1) >> 1;   // yy iteration
            if (b < 128) { rows_x = false; cols_x = true;  pot = f; outp = g; rows_pb = 32; row0g = b * 32; }
            else         { rows_x = false; cols_x = false; pot = (k & 1) ? py1 : py0; outp = (k & 1) ? py0 : py1; avg = true; rows_pb = 32; row0g = (b - 128) * 32; }
        } else {
            int k = h >> 1;         // xx iteration
            if (b < 128) { rows_x = true; cols_x = false; pot = g; outp = f; rows_pb = 32; row0g = b * 32; }
            else         { rows_x = true; cols_x = true;  pot = (k & 1) ? px1 : px0; outp = (k & 1) ? px0 : px1; avg = true; rows_pb = 32; row0g = (b - 128) * 32; }
        }

        // ---- restage G (.w) of the active column pack: (pot - cn) * scale ----
        float4* colpk = cols_x ? packx : packy;
        const float* ccn = cols_x ? cnx : cny;
        for (int j = tid; j < NPT; j += NTHR) {
            float pv = pot ? gload(pot + j) : 0.0f;
            float cn = ccn[j];
            ((float*)&colpk[j])[3] = (pv - cn) * scale;   // ds_write_b32
        }
        __syncthreads();

        // ---- wave tasks: 4 rows x 2048 cols each ----
        const float4* rowpk = rows_x ? packx : packy;
        const int ntask = rows_pb >> 1;          // (rows_pb/4 groups) x 2 halves
        for (int t = wave; t < ntask; t += 16) {
            int grp = t >> 1, half = t & 1;
            int lr0 = grp << 2;
            int r0g = row0g + lr0;
            if (isU) run_task<true >(colpk, rowpk, r0g, half, lane, scale, part2, lr0);
            else     run_task<false>(colpk, rowpk, r0g, half, lane, scale, part2, lr0);
        }
        __syncthreads();

        // ---- finalize: merge 16 partials (max tree + pipelined exp2 sum) ----
        const float* rcn = rows_x ? cnx : cny;
        if (tid < rows_pb) {
            float2 pv2[16];
#pragma unroll
            for (int q = 0; q < 16; ++q) pv2[q] = part2[tid * 16 + q];
            float mm = pv2[0].x;
#pragma unroll
            for (int q = 1; q < 15; q += 2) mm = max3f(mm, pv2[q].x, pv2[q + 1].x);
            mm = fmaxf(mm, pv2[15].x);
            float ss = 0.0f;
#pragma unroll
            for (int q = 0; q < 16; ++q) ss += pv2[q].y * fexp2(pv2[q].x - mm);
            int rg = row0g + tid;
            float rn = rcn[rg];
            float lse2 = mm + flog2(ss) - rn * scale;    // + X_i
            float val;
            if (isU) {
                val = lse2;
            } else {
                val = -E2 * (lse2 - 12.0f);               // log2(4096)=12
                if (avg) val = 0.5f * (gload(pot + rg) + val);
            }
            gstore(outp + rg, val);
        }

        group_barrier(cbarrier, 128u * (unsigned)(h + 1), b);
    }

    // ---- final reduction (block 0; must also wait for group B) ----
    if (b == 0) {
        if (tid == 0) {
            for (;;) {
                unsigned tot = 0;
#pragma unroll
                for (int i = 0; i < 16; ++i)
                    tot += __hip_atomic_load(&ctrB[i * 16],
                                             __ATOMIC_RELAXED, __HIP_MEMORY_SCOPE_SYSTEM);
                if (tot >= 128u * 41u) break;
                __builtin_amdgcn_s_sleep(1);
            }
        }
        __syncthreads();

        float sf = 0.f, sg = 0.f, sx = 0.f, sy = 0.f, um = -1e30f, us = 0.f;
        for (int i = tid; i < NPT; i += NTHR) {
            sf += gload(ffin + i); sg += gload(g + i);
            sx += gload(fxv + i);  sy += gload(fyv + i);
            float v = gload(uls + i);
            float mn = fmaxf(um, v);
            us = us * fexp2(um - mn) + fexp2(v - mn);
            um = mn;
        }
#pragma unroll
        for (int off = 1; off < 64; off <<= 1) {
            sf += __shfl_xor(sf, off, 64);
            sg += __shfl_xor(sg, off, 64);
            sx += __shfl_xor(sx, off, 64);
            sy += __shfl_xor(sy, off, 64);
            float mo = __shfl_xor(um, off, 64);
            float so = __shfl_xor(us, off, 64);
            float mn = fmaxf(um, mo);
            us = us * fexp2(um - mn) + so * fexp2(mo - mn);
            um = mn;
        }
        __syncthreads();
        if (lane == 0) {
            float* red = smem;
            red[wave * 6 + 0] = sf; red[wave * 6 + 1] = sg; red[wave * 6 + 2] = sx;
            red[wave * 6 + 3] = sy; red[wave * 6 + 4] = um; red[wave * 6 + 5] = us;
        }
        __syncthreads();
        if (tid == 0) {
            float* red = smem;
            float Sf = 0, Sg = 0, Sx = 0, Sy = 0, Um = -1e30f, Us = 0;
            for (int w = 0; w < 16; ++w) {
                Sf += red[w * 6 + 0]; Sg += red[w * 6 + 1];
                Sx += red[w * 6 + 2]; Sy += red[w * 6 + 3];
                float mo = red[w * 6 + 4], so = red[w * 6 + 5];
                float mn = fmaxf(Um, mo);
                Us = Us * fexp2(Um - mn) + so * fexp2(mo - mn);
                Um = mn;
            }
            float mean = (Sf + Sg - Sx - Sy) * (1.0f / 4096.0f);
            float U = LN2F * (Um + flog2(Us)) - logf(4096.0f * 4095.0f);
            out[0] = mean + U;
        }
    }
}

extern "C" void kernel_launch(void* const* d_in, const int* in_sizes, int n_in,
                              void* d_out, int out_size, void* d_ws, size_t ws_size,
                              hipStream_t stream) {
    const float* x = (const float*)d_in[0];
    const float* y = (const float*)d_in[1];
    float* ws  = (float*)d_ws;
    float* out = (float*)d_out;

    (void)hipFuncSetAttribute((const void*)sink_main,
                              hipFuncAttributeMaxDynamicSharedMemorySize, SMEM_BYTES);

    sink_init<<<4, 1024, 0, stream>>>(x, y, ws);
    sink_main<<<NBLK, NTHR, SMEM_BYTES, stream>>>(x, y, ws, out);
}